// Round 1
// baseline (111.093 us; speedup 1.0000x reference)
//
#include <hip/hip_runtime.h>

// Problem constants (from reference setup_inputs):
// x: (L=2, B=16, T=512, H=12) f32 ; cuts: (12,1) f32 ; leaf_score: (4096,1000) f32
// out: (16,1000) f32
#define HF 12
#define NLEAF 4096
#define NB 16
#define NT 512
#define NC 1000
#define TCHUNK 64
#define NTCHUNK (NT / TCHUNK)   // 8

#define CTILE 256
#define LCHUNK 128
#define NCTILE 4                 // ceil(1000/256)
#define NLCHUNK (NLEAF / LCHUNK) // 32

// ---------------------------------------------------------------------------
// Kernel 1: S[b][l] = sum over t of leaf[b,t,l]
// leaf[b,t,l] = prod_i h[i][bit_i],  bit_i = (l >> (11-i)) & 1
// Factor: l = hi*64 + lo ; P_hi over features 0..5, P_lo over features 6..11.
// Grid: NB*NTCHUNK blocks of 256 threads; atomicAdd partials into S.
// ---------------------------------------------------------------------------
__global__ __launch_bounds__(256) void ndt_leaf_kernel(
    const float* __restrict__ x, const float* __restrict__ cuts,
    float* __restrict__ S) {
  const int b   = blockIdx.x / NTCHUNK;
  const int tc  = blockIdx.x % NTCHUNK;
  const int tid = threadIdx.x;

  __shared__ float h0[HF], h1[HF];
  __shared__ float Phi[64], Plo[64];

  float acc[16];
#pragma unroll
  for (int k = 0; k < 16; ++k) acc[k] = 0.f;

  // last layer of x: offset (L-1)*B*T*H
  const float* xb = x + (size_t)NB * NT * HF + (size_t)b * NT * HF;

  for (int tt = 0; tt < TCHUNK; ++tt) {
    const int t = tc * TCHUNK + tt;
    if (tid < HF) {
      const float xv = xb[(size_t)t * HF + tid];
      h0[tid] = xv;                       // W[0]=1, b0=0
      h1[tid] = 2.f * xv - cuts[tid];     // W[1]=2, b1=-cut_i
    }
    __syncthreads();
    if (tid < 128) {
      const int idx  = tid & 63;
      const int base = (tid < 64) ? 0 : 6;
      float p = 1.f;
#pragma unroll
      for (int i = 0; i < 6; ++i) {
        const int bit = (idx >> (5 - i)) & 1;
        const int f   = base + i;
        p *= bit ? h1[f] : h0[f];
      }
      if (tid < 64) Phi[idx] = p; else Plo[idx] = p;
    }
    __syncthreads();
#pragma unroll
    for (int k = 0; k < 16; ++k) {
      const int l = k * 256 + tid;
      acc[k] += Phi[l >> 6] * Plo[l & 63];
    }
    // no barrier needed here: next iter's h-writes touch h0/h1 (not P*),
    // and P* writes only happen after the first barrier of the next iter.
  }

  float* Sb = S + (size_t)b * NLEAF;
#pragma unroll
  for (int k = 0; k < 16; ++k) {
    atomicAdd(&Sb[k * 256 + tid], acc[k]);
  }
}

// ---------------------------------------------------------------------------
// Kernel 2: out[b][c] += sum_{l in chunk} (S[b][l]/T) * score[l][c]
// Grid: NCTILE*NLCHUNK = 128 blocks of 256 threads.
// Each block stages S[0:16][lchunk] into LDS (8 KB); score read exactly once
// across the whole grid.
// ---------------------------------------------------------------------------
__global__ __launch_bounds__(256) void ndt_gemm_kernel(
    const float* __restrict__ S, const float* __restrict__ score,
    float* __restrict__ out) {
  const int ct  = blockIdx.x / NLCHUNK;
  const int lc  = blockIdx.x % NLCHUNK;
  const int tid = threadIdx.x;
  const int c   = ct * CTILE + tid;

  __shared__ float Sl[NB][LCHUNK];
  for (int i = tid; i < NB * LCHUNK; i += 256) {
    const int bb = i / LCHUNK;
    const int ll = i % LCHUNK;
    Sl[bb][ll] = S[(size_t)bb * NLEAF + lc * LCHUNK + ll] * (1.f / NT);
  }
  __syncthreads();

  if (c < NC) {
    float acc[NB];
#pragma unroll
    for (int bb = 0; bb < NB; ++bb) acc[bb] = 0.f;

    const float* sc = score + (size_t)(lc * LCHUNK) * NC + c;
#pragma unroll 4
    for (int l = 0; l < LCHUNK; ++l) {
      const float sv = sc[(size_t)l * NC];
#pragma unroll
      for (int bb = 0; bb < NB; ++bb) acc[bb] += Sl[bb][l] * sv;
    }
#pragma unroll
    for (int bb = 0; bb < NB; ++bb) {
      atomicAdd(&out[bb * NC + c], acc[bb]);
    }
  }
}

extern "C" void kernel_launch(void* const* d_in, const int* in_sizes, int n_in,
                              void* d_out, int out_size, void* d_ws, size_t ws_size,
                              hipStream_t stream) {
  const float* x     = (const float*)d_in[0];
  const float* cuts  = (const float*)d_in[1];
  const float* score = (const float*)d_in[2];
  float* out = (float*)d_out;
  float* S   = (float*)d_ws;  // NB*NLEAF floats = 256 KB

  // zero the accumulators (ws and out are poisoned with 0xAA before each call)
  hipMemsetAsync(S, 0, (size_t)NB * NLEAF * sizeof(float), stream);
  hipMemsetAsync(out, 0, (size_t)NB * NC * sizeof(float), stream);

  ndt_leaf_kernel<<<NB * NTCHUNK, 256, 0, stream>>>(x, cuts, S);
  ndt_gemm_kernel<<<NCTILE * NLCHUNK, 256, 0, stream>>>(S, score, out);
}

// Round 5
// 95.827 us; speedup vs baseline: 1.1593x; 1.1593x over previous
//
#include <hip/hip_runtime.h>

// x: (2, 16, 512, 12) f32 ; cuts: (12,1) f32 ; leaf_score: (4096,1000) f32
// out: (16,1000) f32
// leaf[b,t,l] = prod_i h[i][bit_i(l)], h[i][0]=x, h[i][1]=2x-cut_i
// out[b,c] = sum_l (1/T * sum_t leaf[b,t,l]) * score[l,c]
#define HF 12
#define NLEAF 4096
#define NB 16
#define NT 512
#define NC 1000
#define NTC 8                 // t-chunks per b
#define TCH 64                // t per block
#define TSUB 16               // t per phase
#define NSUB (TCH / TSUB)     // 4 phases
#define LCH 64                // l per k2 block
#define NLCH (NLEAF / LCH)    // 64
#define NCT 4                 // c-tiles of 256
#define INVT (1.0f / 512.0f)

// ---------------------------------------------------------------------------
// k1: partial S. grid = NB*NTC = 128 blocks (blk = b*8+tc), 256 threads.
// Sp[blk][l] = sum over this block's 64 t of leaf[b,t,l]. Plain stores.
// ---------------------------------------------------------------------------
__global__ __launch_bounds__(256) void k1_leaf(const float* __restrict__ x,
                                               const float* __restrict__ cuts,
                                               float* __restrict__ Sp) {
  const int blk = blockIdx.x;
  const int tid = threadIdx.x;

  __shared__ float h0s[TSUB][HF], h1s[TSUB][HF];
  __shared__ float Phis[TSUB][64], Plos[TSUB][64];

  // x[-1] layer, this block's 64 t rows: offset b*512*12 + tc*64*12 = blk*768
  const float* xb = x + (size_t)NB * NT * HF + (size_t)blk * (TCH * HF);

  const int  tl  = tid / HF;
  const int  f   = tid - tl * HF;
  const bool ldr = (tid < TSUB * HF);   // 192 loader threads
  const float cf = ldr ? cuts[f] : 0.f;
  float xv = ldr ? xb[tid] : 0.f;       // prefetched phase-0 x

  float acc[16];
#pragma unroll
  for (int k = 0; k < 16; ++k) acc[k] = 0.f;

  const int w  = tid >> 6;   // wave id 0..3
  const int lo = tid & 63;

  for (int ts = 0; ts < NSUB; ++ts) {
    if (ldr) {
      h0s[tl][f] = xv;
      h1s[tl][f] = 2.f * xv - cf;
    }
    __syncthreads();
    if (ldr && ts + 1 < NSUB) xv = xb[(ts + 1) * TSUB * HF + tid];  // prefetch

    // P-compute: 2048 tasks = 16 t * (hi|lo) * 64, 8 per thread.
    // Wave-uniform t2/half -> h reads are LDS broadcasts.
#pragma unroll
    for (int r = 0; r < 8; ++r) {
      const int task = r * 256 + tid;
      const int t2   = task >> 7;
      const int half = (task >> 6) & 1;
      const int idx  = task & 63;
      const float* hh0 = h0s[t2];
      const float* hh1 = h1s[t2];
      float p = 1.f;
#pragma unroll
      for (int i = 0; i < 6; ++i) {
        const int ff  = half * 6 + i;
        const int bit = (idx >> (5 - i)) & 1;
        p *= bit ? hh1[ff] : hh0[ff];
      }
      if (half) Plos[t2][idx] = p;
      else      Phis[t2][(idx & 3) * 16 + (idx >> 2)] = p;  // permuted for b128 read
    }
    __syncthreads();

    // accumulate: l = k*256+tid -> hi = 4k+w, lo = tid&63
#pragma unroll
    for (int t2 = 0; t2 < TSUB; ++t2) {
      const float  plo = Plos[t2][lo];
      const float4* ph = (const float4*)&Phis[t2][w * 16];  // broadcast reads
      const float4 p0 = ph[0], p1 = ph[1], p2 = ph[2], p3 = ph[3];
      acc[0]  += p0.x * plo;  acc[1]  += p0.y * plo;
      acc[2]  += p0.z * plo;  acc[3]  += p0.w * plo;
      acc[4]  += p1.x * plo;  acc[5]  += p1.y * plo;
      acc[6]  += p1.z * plo;  acc[7]  += p1.w * plo;
      acc[8]  += p2.x * plo;  acc[9]  += p2.y * plo;
      acc[10] += p2.z * plo;  acc[11] += p2.w * plo;
      acc[12] += p3.x * plo;  acc[13] += p3.y * plo;
      acc[14] += p3.z * plo;  acc[15] += p3.w * plo;
    }
  }

  float* sp = Sp + (size_t)blk * NLEAF;
#pragma unroll
  for (int k = 0; k < 16; ++k) sp[k * 256 + tid] = acc[k];
}

// ---------------------------------------------------------------------------
// k1.5: St[l][b] = (1/T) * sum_tc Sp[b*8+tc][l]. grid = 16 blocks * 256.
// ---------------------------------------------------------------------------
__global__ __launch_bounds__(256) void k15_sum(const float* __restrict__ Sp,
                                               float* __restrict__ St) {
  const int l = blockIdx.x * 256 + threadIdx.x;
  float s[NB];
#pragma unroll
  for (int b = 0; b < NB; ++b) {
    float v = 0.f;
#pragma unroll
    for (int tc = 0; tc < NTC; ++tc)
      v += Sp[(size_t)(b * NTC + tc) * NLEAF + l];
    s[b] = v * INVT;
  }
  float4* o = (float4*)&St[(size_t)l * NB];
  o[0] = make_float4(s[0],  s[1],  s[2],  s[3]);
  o[1] = make_float4(s[4],  s[5],  s[6],  s[7]);
  o[2] = make_float4(s[8],  s[9],  s[10], s[11]);
  o[3] = make_float4(s[12], s[13], s[14], s[15]);
}

// ---------------------------------------------------------------------------
// k2: pout[lc][c][b] = sum_{l in chunk} St[l][b] * score[l][c].
// grid = NCT*NLCH = 256 blocks, 256 threads (thread = c). St rows are
// wave-uniform -> scalar loads; score read exactly once. Plain stores.
// ---------------------------------------------------------------------------
__global__ __launch_bounds__(256) void k2_gemm(const float* __restrict__ St,
                                               const float* __restrict__ score,
                                               float* __restrict__ pout) {
  const int ct = blockIdx.x / NLCH;
  const int lc = blockIdx.x % NLCH;
  const int c  = ct * 256 + threadIdx.x;
  if (c >= NC) return;

  float acc[NB];
#pragma unroll
  for (int b = 0; b < NB; ++b) acc[b] = 0.f;

#pragma unroll 4
  for (int l = 0; l < LCH; ++l) {
    const int gl = lc * LCH + l;
    const float sv = score[(size_t)gl * NC + c];
    const float4* sr = (const float4*)&St[(size_t)gl * NB];  // uniform -> s_load
    const float4 a0 = sr[0], a1 = sr[1], a2 = sr[2], a3 = sr[3];
    acc[0]  += a0.x * sv;  acc[1]  += a0.y * sv;
    acc[2]  += a0.z * sv;  acc[3]  += a0.w * sv;
    acc[4]  += a1.x * sv;  acc[5]  += a1.y * sv;
    acc[6]  += a1.z * sv;  acc[7]  += a1.w * sv;
    acc[8]  += a2.x * sv;  acc[9]  += a2.y * sv;
    acc[10] += a2.z * sv;  acc[11] += a2.w * sv;
    acc[12] += a3.x * sv;  acc[13] += a3.y * sv;
    acc[14] += a3.z * sv;  acc[15] += a3.w * sv;
  }

  float4* po = (float4*)&pout[((size_t)lc * NC + c) * NB];
  po[0] = make_float4(acc[0],  acc[1],  acc[2],  acc[3]);
  po[1] = make_float4(acc[4],  acc[5],  acc[6],  acc[7]);
  po[2] = make_float4(acc[8],  acc[9],  acc[10], acc[11]);
  po[3] = make_float4(acc[12], acc[13], acc[14], acc[15]);
}

// ---------------------------------------------------------------------------
// k3: out[b][c] = sum_lc pout[lc][c][b]. grid = 63 blocks * 256.
// ---------------------------------------------------------------------------
__global__ __launch_bounds__(256) void k3_red(const float* __restrict__ pout,
                                              float* __restrict__ out) {
  const int gid = blockIdx.x * 256 + threadIdx.x;
  if (gid >= NB * NC) return;
  const int b = gid / NC;
  const int c = gid - b * NC;
  float v = 0.f;
#pragma unroll 8
  for (int lc = 0; lc < NLCH; ++lc)
    v += pout[((size_t)lc * NC + c) * NB + b];
  out[gid] = v;
}

extern "C" void kernel_launch(void* const* d_in, const int* in_sizes, int n_in,
                              void* d_out, int out_size, void* d_ws, size_t ws_size,
                              hipStream_t stream) {
  const float* x     = (const float*)d_in[0];
  const float* cuts  = (const float*)d_in[1];
  const float* score = (const float*)d_in[2];
  float* out = (float*)d_out;

  float* Sp = (float*)d_ws;                       // [128][4096]   2 MB
  float* St = Sp + (size_t)NB * NTC * NLEAF;      // [4096][16]  256 KB
  float* po = St + (size_t)NLEAF * NB;            // [64][1000][16] 4 MB

  k1_leaf<<<NB * NTC, 256, 0, stream>>>(x, cuts, Sp);
  k15_sum<<<NLEAF / 256, 256, 0, stream>>>(Sp, St);
  k2_gemm<<<NCT * NLCH, 256, 0, stream>>>(St, score, po);
  k3_red<<<(NB * NC + 255) / 256, 256, 0, stream>>>(po, out);
}

// Round 7
// 88.120 us; speedup vs baseline: 1.2607x; 1.0875x over previous
//
#include <hip/hip_runtime.h>

// x: (2, 16, 512, 12) f32 ; cuts: (12,1) f32 ; leaf_score: (4096,1000) f32
// out: (16,1000) f32
// leaf[b,t,l] = prod_i h[i][bit_i(l)], h[i][0]=x, h[i][1]=2x-cut_i
// out[b,c] = sum_l (1/T * sum_t leaf[b,t,l]) * score[l,c]
#define HF 12
#define NLEAF 4096
#define NB 16
#define NT 512
#define NC 1000
#define NTC 8                 // t-chunks per b
#define TCH 64                // t per block
#define TSUB 16               // t per phase
#define NSUB (TCH / TSUB)     // 4 phases
#define LCH 64                // l per k2 block
#define NLCH (NLEAF / LCH)    // 64
#define NCT 4                 // c-tiles of 256
#define INVT (1.0f / 512.0f)

// ---------------------------------------------------------------------------
// k1: partial S. grid = NB*NTC = 128 blocks (blk = b*8+tc), 256 threads.
// Sp[blk][l] = sum over this block's 64 t of leaf[b,t,l]. Plain stores.
// ---------------------------------------------------------------------------
__global__ __launch_bounds__(256) void k1_leaf(const float* __restrict__ x,
                                               const float* __restrict__ cuts,
                                               float* __restrict__ Sp) {
  const int blk = blockIdx.x;
  const int tid = threadIdx.x;

  __shared__ float h0s[TSUB][HF], h1s[TSUB][HF];
  __shared__ float Phis[TSUB][64], Plos[TSUB][64];

  const float* xb = x + (size_t)NB * NT * HF + (size_t)blk * (TCH * HF);

  const int  tl  = tid / HF;
  const int  f   = tid - tl * HF;
  const bool ldr = (tid < TSUB * HF);   // 192 loader threads
  const float cf = ldr ? cuts[f] : 0.f;
  float xv = ldr ? xb[tid] : 0.f;       // prefetched phase-0 x

  float acc[16];
#pragma unroll
  for (int k = 0; k < 16; ++k) acc[k] = 0.f;

  const int w  = tid >> 6;   // wave id 0..3
  const int lo = tid & 63;

  for (int ts = 0; ts < NSUB; ++ts) {
    if (ldr) {
      h0s[tl][f] = xv;
      h1s[tl][f] = 2.f * xv - cf;
    }
    __syncthreads();
    if (ldr && ts + 1 < NSUB) xv = xb[(ts + 1) * TSUB * HF + tid];  // prefetch

    // P-compute: 2048 tasks = 16 t * (hi|lo) * 64, 8 per thread.
#pragma unroll
    for (int r = 0; r < 8; ++r) {
      const int task = r * 256 + tid;
      const int t2   = task >> 7;
      const int half = (task >> 6) & 1;
      const int idx  = task & 63;
      const float* hh0 = h0s[t2];
      const float* hh1 = h1s[t2];
      float p = 1.f;
#pragma unroll
      for (int i = 0; i < 6; ++i) {
        const int ff  = half * 6 + i;
        const int bit = (idx >> (5 - i)) & 1;
        p *= bit ? hh1[ff] : hh0[ff];
      }
      if (half) Plos[t2][idx] = p;
      else      Phis[t2][(idx & 3) * 16 + (idx >> 2)] = p;  // permuted for b128 read
    }
    __syncthreads();

#pragma unroll
    for (int t2 = 0; t2 < TSUB; ++t2) {
      const float  plo = Plos[t2][lo];
      const float4* ph = (const float4*)&Phis[t2][w * 16];  // broadcast reads
      const float4 p0 = ph[0], p1 = ph[1], p2 = ph[2], p3 = ph[3];
      acc[0]  += p0.x * plo;  acc[1]  += p0.y * plo;
      acc[2]  += p0.z * plo;  acc[3]  += p0.w * plo;
      acc[4]  += p1.x * plo;  acc[5]  += p1.y * plo;
      acc[6]  += p1.z * plo;  acc[7]  += p1.w * plo;
      acc[8]  += p2.x * plo;  acc[9]  += p2.y * plo;
      acc[10] += p2.z * plo;  acc[11] += p2.w * plo;
      acc[12] += p3.x * plo;  acc[13] += p3.y * plo;
      acc[14] += p3.z * plo;  acc[15] += p3.w * plo;
    }
  }

  float* sp = Sp + (size_t)blk * NLEAF;
#pragma unroll
  for (int k = 0; k < 16; ++k) sp[k * 256 + tid] = acc[k];
}

// ---------------------------------------------------------------------------
// k2f: fused (k15 + gemm). grid = NLCH*NCT = 256 blocks, 256 threads.
// Block (lc,ct): reduce Sp partials for its 64-l chunk into LDS Stl[b][ll]
// (writes lane-contiguous -> conflict-free; reads same-addr b128 broadcast),
// then pout[lc][b][c] = sum_l Stl[b][l] * score[l][c]. Coalesced stores.
// ---------------------------------------------------------------------------
__global__ __launch_bounds__(256) void k2f(const float* __restrict__ Sp,
                                           const float* __restrict__ score,
                                           float* __restrict__ pout) {
  const int lc  = blockIdx.x / NCT;   // ct-blocks with same lc adjacent (L2 reuse)
  const int ct  = blockIdx.x % NCT;
  const int tid = threadIdx.x;

  __shared__ float Stl[NB][LCH];      // 4 KB

  for (int i = tid; i < NB * LCH; i += 256) {
    const int b  = i >> 6;
    const int ll = i & 63;
    const float* sp = Sp + (size_t)(b * NTC) * NLEAF + lc * LCH + ll;
    float v = 0.f;
#pragma unroll
    for (int tc = 0; tc < NTC; ++tc) v += sp[(size_t)tc * NLEAF];
    Stl[b][ll] = v * INVT;
  }
  __syncthreads();

  const int c = ct * 256 + tid;
  if (c < NC) {
    float acc[NB];
#pragma unroll
    for (int b = 0; b < NB; ++b) acc[b] = 0.f;

    const float* sc = score + (size_t)(lc * LCH) * NC + c;
    for (int l0 = 0; l0 < LCH; l0 += 8) {
      float sv[8];
#pragma unroll
      for (int j = 0; j < 8; ++j) sv[j] = sc[(size_t)(l0 + j) * NC];
#pragma unroll
      for (int b = 0; b < NB; ++b) {
        const float4* r = (const float4*)&Stl[b][l0];  // 32B-aligned broadcast
        const float4 r0 = r[0], r1 = r[1];
        acc[b] += r0.x * sv[0] + r0.y * sv[1] + r0.z * sv[2] + r0.w * sv[3]
                + r1.x * sv[4] + r1.y * sv[5] + r1.z * sv[6] + r1.w * sv[7];
      }
    }
#pragma unroll
    for (int b = 0; b < NB; ++b)
      pout[((size_t)lc * NB + b) * NC + c] = acc[b];   // coalesced
  }
}

// ---------------------------------------------------------------------------
// k3: out[b][c] = sum_lc pout[lc][b][c]. grid = 63 blocks * 256. Coalesced.
// ---------------------------------------------------------------------------
__global__ __launch_bounds__(256) void k3_red(const float* __restrict__ pout,
                                              float* __restrict__ out) {
  const int gid = blockIdx.x * 256 + threadIdx.x;
  if (gid >= NB * NC) return;
  const int b = gid / NC;
  const int c = gid - b * NC;
  float v = 0.f;
#pragma unroll 8
  for (int lc = 0; lc < NLCH; ++lc)
    v += pout[((size_t)lc * NB + b) * NC + c];
  out[gid] = v;
}

extern "C" void kernel_launch(void* const* d_in, const int* in_sizes, int n_in,
                              void* d_out, int out_size, void* d_ws, size_t ws_size,
                              hipStream_t stream) {
  const float* x     = (const float*)d_in[0];
  const float* cuts  = (const float*)d_in[1];
  const float* score = (const float*)d_in[2];
  float* out = (float*)d_out;

  float* Sp = (float*)d_ws;                       // [128][4096]     2 MB
  float* po = Sp + (size_t)NB * NTC * NLEAF;      // [64][16][1000]  4 MB

  k1_leaf<<<NB * NTC, 256, 0, stream>>>(x, cuts, Sp);
  k2f<<<NLCH * NCT, 256, 0, stream>>>(Sp, score, po);
  k3_red<<<(NB * NC + 255) / 256, 256, 0, stream>>>(po, out);
}

// Round 8
// 85.250 us; speedup vs baseline: 1.3031x; 1.0337x over previous
//
#include <hip/hip_runtime.h>

// x: (2, 16, 512, 12) f32 ; cuts: (12,1) f32 ; leaf_score: (4096,1000) f32
// out: (16,1000) f32
// leaf[b,t,l] = prod_i h[i][bit_i(l)], h[i][0]=x, h[i][1]=2x-cut_i
// out[b,c] = sum_l (1/T * sum_t leaf[b,t,l]) * score[l,c]
#define HF 12
#define NLEAF 4096
#define NB 16
#define NT 512
#define NC 1000
#define NTC 8                 // t-chunks per b
#define TCH 64                // t per block
#define TSUB 16               // t per phase
#define NSUB (TCH / TSUB)     // 4 phases
#define LCH 64                // l per k2 block
#define NLCH (NLEAF / LCH)    // 64
#define NCT 4                 // c-tiles of 256
#define INVT (1.0f / 512.0f)

// ---------------------------------------------------------------------------
// k1: partial S. grid = NB*NTC = 128 blocks (blk = b*8+tc), 256 threads.
// Sp[blk][l] = sum over this block's 64 t of leaf[b,t,l]. Plain stores.
// ---------------------------------------------------------------------------
__global__ __launch_bounds__(256) void k1_leaf(const float* __restrict__ x,
                                               const float* __restrict__ cuts,
                                               float* __restrict__ Sp) {
  const int blk = blockIdx.x;
  const int tid = threadIdx.x;

  __shared__ float h0s[TSUB][HF], h1s[TSUB][HF];
  __shared__ float Phis[TSUB][64], Plos[TSUB][64];

  const float* xb = x + (size_t)NB * NT * HF + (size_t)blk * (TCH * HF);

  const int  tl  = tid / HF;
  const int  f   = tid - tl * HF;
  const bool ldr = (tid < TSUB * HF);   // 192 loader threads
  const float cf = ldr ? cuts[f] : 0.f;
  float xv = ldr ? xb[tid] : 0.f;       // prefetched phase-0 x

  float acc[16];
#pragma unroll
  for (int k = 0; k < 16; ++k) acc[k] = 0.f;

  const int w  = tid >> 6;   // wave id 0..3
  const int lo = tid & 63;

  for (int ts = 0; ts < NSUB; ++ts) {
    if (ldr) {
      h0s[tl][f] = xv;
      h1s[tl][f] = 2.f * xv - cf;
    }
    __syncthreads();
    if (ldr && ts + 1 < NSUB) xv = xb[(ts + 1) * TSUB * HF + tid];  // prefetch

    // P-compute: 2048 tasks = 16 t * (hi|lo) * 64, 8 per thread.
#pragma unroll
    for (int r = 0; r < 8; ++r) {
      const int task = r * 256 + tid;
      const int t2   = task >> 7;
      const int half = (task >> 6) & 1;
      const int idx  = task & 63;
      const float* hh0 = h0s[t2];
      const float* hh1 = h1s[t2];
      float p = 1.f;
#pragma unroll
      for (int i = 0; i < 6; ++i) {
        const int ff  = half * 6 + i;
        const int bit = (idx >> (5 - i)) & 1;
        p *= bit ? hh1[ff] : hh0[ff];
      }
      if (half) Plos[t2][idx] = p;
      else      Phis[t2][(idx & 3) * 16 + (idx >> 2)] = p;  // permuted for b128 read
    }
    __syncthreads();

#pragma unroll
    for (int t2 = 0; t2 < TSUB; ++t2) {
      const float  plo = Plos[t2][lo];
      const float4* ph = (const float4*)&Phis[t2][w * 16];  // broadcast reads
      const float4 p0 = ph[0], p1 = ph[1], p2 = ph[2], p3 = ph[3];
      acc[0]  += p0.x * plo;  acc[1]  += p0.y * plo;
      acc[2]  += p0.z * plo;  acc[3]  += p0.w * plo;
      acc[4]  += p1.x * plo;  acc[5]  += p1.y * plo;
      acc[6]  += p1.z * plo;  acc[7]  += p1.w * plo;
      acc[8]  += p2.x * plo;  acc[9]  += p2.y * plo;
      acc[10] += p2.z * plo;  acc[11] += p2.w * plo;
      acc[12] += p3.x * plo;  acc[13] += p3.y * plo;
      acc[14] += p3.z * plo;  acc[15] += p3.w * plo;
    }
  }

  float* sp = Sp + (size_t)blk * NLEAF;
#pragma unroll
  for (int k = 0; k < 16; ++k) sp[k * 256 + tid] = acc[k];
}

// ---------------------------------------------------------------------------
// k2f: fused (k15 + gemm + out-reduce). grid = NLCH*NCT = 256 blocks.
// Block (lc,ct): reduce Sp partials for its 64-l chunk into LDS Stl[b][ll],
// then acc[b] = sum_l Stl[b][l] * score[l][c], atomicAdd into out[b][c].
// out must be zeroed first (memset in kernel_launch).
// ---------------------------------------------------------------------------
__global__ __launch_bounds__(256) void k2f(const float* __restrict__ Sp,
                                           const float* __restrict__ score,
                                           float* __restrict__ out) {
  const int lc  = blockIdx.x / NCT;   // ct-blocks with same lc adjacent (L2 reuse)
  const int ct  = blockIdx.x % NCT;
  const int tid = threadIdx.x;

  __shared__ float Stl[NB][LCH];      // 4 KB

  for (int i = tid; i < NB * LCH; i += 256) {
    const int b  = i >> 6;
    const int ll = i & 63;
    const float* sp = Sp + (size_t)(b * NTC) * NLEAF + lc * LCH + ll;
    float v = 0.f;
#pragma unroll
    for (int tc = 0; tc < NTC; ++tc) v += sp[(size_t)tc * NLEAF];
    Stl[b][ll] = v * INVT;
  }
  __syncthreads();

  const int c = ct * 256 + tid;
  if (c < NC) {
    float acc[NB];
#pragma unroll
    for (int b = 0; b < NB; ++b) acc[b] = 0.f;

    const float* sc = score + (size_t)(lc * LCH) * NC + c;
    for (int l0 = 0; l0 < LCH; l0 += 8) {
      float sv[8];
#pragma unroll
      for (int j = 0; j < 8; ++j) sv[j] = sc[(size_t)(l0 + j) * NC];
#pragma unroll
      for (int b = 0; b < NB; ++b) {
        const float4* r = (const float4*)&Stl[b][l0];  // 32B-aligned broadcast
        const float4 r0 = r[0], r1 = r[1];
        acc[b] += r0.x * sv[0] + r0.y * sv[1] + r0.z * sv[2] + r0.w * sv[3]
                + r1.x * sv[4] + r1.y * sv[5] + r1.z * sv[6] + r1.w * sv[7];
      }
    }
#pragma unroll
    for (int b = 0; b < NB; ++b)
      atomicAdd(&out[b * NC + c], acc[b]);  // coalesced addresses per wave
  }
}

extern "C" void kernel_launch(void* const* d_in, const int* in_sizes, int n_in,
                              void* d_out, int out_size, void* d_ws, size_t ws_size,
                              hipStream_t stream) {
  const float* x     = (const float*)d_in[0];
  const float* cuts  = (const float*)d_in[1];
  const float* score = (const float*)d_in[2];
  float* out = (float*)d_out;

  float* Sp = (float*)d_ws;   // [128][4096]  2 MB

  hipMemsetAsync(out, 0, (size_t)NB * NC * sizeof(float), stream);
  k1_leaf<<<NB * NTC, 256, 0, stream>>>(x, cuts, Sp);
  k2f<<<NLCH * NCT, 256, 0, stream>>>(Sp, score, out);
}